// Round 7
// baseline (1350.130 us; speedup 1.0000x reference)
//
#include <hip/hip_runtime.h>
#include <hip/hip_fp16.h>

// GCN 3-layer, PUSH-mode layers with LDS-staged src windows (R20).
// Build: count1/scan -> region bases; scatter1 (in-LDS counting sort) sorts
// edges by dst-superbucket (4096 nodes) into pk1; buildpush re-sorts each
// region by src-superbucket (128 buckets) into pk2, computes degrees ->
// dinv + z1 (half2), writes tile bounds tb[reg][srcSB].
// R19 failed (360us push_f4): per-edge z gathers thrashed 32KB L1 (2 windows
// + pk2 stream), fell to the L2 random-request wall (R18) with worse ILP.
// R20: block = (dstRegion, srcHalf) [246 blocks, 1024 thr]; acc[4096 x F]
// fp32 in LDS; per cell (4096 src nodes) the z window is STAGED INTO LDS
// with coalesced loads (256-512 line-reqs vs ~1016 random), next window
// prefetched to regs under current cell's work. Per edge: coalesced pk2
// read + 1 LDS read + F LDS atomicAdd. L2 sees only coalesced traffic.
// f4 layer: 96KB LDS (dynamic + hipFuncSetAttribute; gfx950 allows 160KB).
// Partials (2/region) merged in fin kernels with self-term + dinv + W/tanh.
// partial aliases pk1 (dead after buildpush).
// Math per layer (input u): z = u*dinv; s_i = sum_{e:dst=i} z[src_e];
//   out_i = (dinv_i*(s_i + z_i)) @ W + b   (self-loop folds into s+z).
// pk = (dst&4095) | (src<<12); srcSB = pk>>24 (src 19 bits); loc src = (pk>>12)&4095.

#define TPB 256
#define T_TILE 16384
#define SBB 12           // superbucket = 4096 nodes
#define NSB_MAX 128

// ---------------- pass 0: per-tile superbucket histogram ----------------

__global__ void __launch_bounds__(512)
count1(const int* __restrict__ dst, int* __restrict__ cnt1, int ntB, int E, int SB) {
    __shared__ int hist[NSB_MAX];
    int blk = blockIdx.x, tid = threadIdx.x;
    if (tid < SB) hist[tid] = 0;
    __syncthreads();
    int base = blk * T_TILE;
    #pragma unroll 8
    for (int it = 0; it < T_TILE / 512; ++it) {
        int e = base + it * 512 + tid;
        if (e < E) atomicAdd(&hist[((unsigned)dst[e]) >> SBB], 1);
    }
    __syncthreads();
    if (tid < SB) cnt1[(size_t)tid * ntB + blk] = hist[tid];
}

// ---- 3-kernel exclusive scan over data[len] (in-place), 1024 elems/block ----
__global__ void scan_k1(const int* __restrict__ data, int* __restrict__ bsum, int len) {
    __shared__ int lds[TPB];
    int b = blockIdx.x, t = threadIdx.x;
    int base = b * 1024 + t * 4;
    int s = 0;
    #pragma unroll
    for (int j = 0; j < 4; ++j) { int i = base + j; if (i < len) s += data[i]; }
    lds[t] = s; __syncthreads();
    for (int off = 128; off > 0; off >>= 1) {
        if (t < off) lds[t] += lds[t + off];
        __syncthreads();
    }
    if (t == 0) bsum[b] = lds[0];
}

__global__ void scan_k2(int* __restrict__ bsum, int NB) {
    __shared__ int lds[1024];
    int t = threadIdx.x;
    int v = (t < NB) ? bsum[t] : 0;
    lds[t] = v; __syncthreads();
    for (int off = 1; off < 1024; off <<= 1) {
        int add = (t >= off) ? lds[t - off] : 0;
        __syncthreads();
        lds[t] += add;
        __syncthreads();
    }
    if (t < NB) bsum[t] = lds[t] - v;  // exclusive
}

__global__ void scan_k3(int* __restrict__ data, const int* __restrict__ bsum, int len) {
    __shared__ int lds[TPB];
    int b = blockIdx.x, t = threadIdx.x;
    int base = b * 1024 + t * 4;
    int v[4]; int s = 0;
    #pragma unroll
    for (int j = 0; j < 4; ++j) { int i = base + j; v[j] = (i < len) ? data[i] : 0; s += v[j]; }
    int orig = s;
    lds[t] = s; __syncthreads();
    for (int off = 1; off < 256; off <<= 1) {
        int add = (t >= off) ? lds[t - off] : 0;
        __syncthreads();
        lds[t] += add;
        __syncthreads();
    }
    int run = bsum[b] + lds[t] - orig;
    #pragma unroll
    for (int j = 0; j < 4; ++j) {
        int i = base + j;
        if (i < len) { data[i] = run; run += v[j]; }
    }
}

__global__ void bases_fix(const int* __restrict__ cnt1, int ntB, int SB,
                          int* __restrict__ bases1, int E) {
    int t = threadIdx.x;
    if (t < SB) bases1[t] = cnt1[(size_t)t * ntB];
    if (t == 0) bases1[SB] = E;
}

// ---- pass 1: in-LDS counting-sort scatter (coalesced write-back, R16) ----
__global__ void __launch_bounds__(512)
scatter1(const int* __restrict__ dst, const int* __restrict__ src,
         const int* __restrict__ cnt1, unsigned* __restrict__ pk1,
         int ntB, int E, int SB) {
    __shared__ unsigned lpk[T_TILE];   // 64KB staged packed values
    __shared__ int lhist[NSB_MAX];
    __shared__ int lexcl[NSB_MAX];
    __shared__ int lcur[NSB_MAX];
    __shared__ int basec[NSB_MAX];
    int blk = blockIdx.x, tid = threadIdx.x;
    if (tid < NSB_MAX) lhist[tid] = 0;
    if (tid < SB) basec[tid] = cnt1[(size_t)tid * ntB + blk];
    __syncthreads();
    int base = blk * T_TILE;
    #pragma unroll 8
    for (int it = 0; it < T_TILE / 512; ++it) {
        int e = base + it * 512 + tid;
        if (e < E) atomicAdd(&lhist[((unsigned)dst[e]) >> SBB], 1);
    }
    __syncthreads();
    int hv = (tid < NSB_MAX) ? lhist[tid] : 0;
    if (tid < NSB_MAX) lexcl[tid] = hv;
    __syncthreads();
    for (int off = 1; off < NSB_MAX; off <<= 1) {
        int a = (tid < NSB_MAX && tid >= off) ? lexcl[tid - off] : 0;
        __syncthreads();
        if (tid < NSB_MAX) lexcl[tid] += a;
        __syncthreads();
    }
    if (tid < NSB_MAX) { lexcl[tid] -= hv; lcur[tid] = lexcl[tid]; }
    __syncthreads();
    #pragma unroll 8
    for (int it = 0; it < T_TILE / 512; ++it) {
        int e = base + it * 512 + tid;
        if (e < E) {
            unsigned d = (unsigned)dst[e];
            unsigned s = (unsigned)src[e];
            int pos = atomicAdd(&lcur[d >> SBB], 1);
            lpk[pos] = (d & 4095u) | (s << SBB);
        }
    }
    __syncthreads();
    for (int b = 0; b < SB; ++b) {
        int lo = lexcl[b], cntb = lhist[b], gb = basec[b];
        for (int t2 = tid; t2 < cntb; t2 += 512)
            pk1[gb + t2] = lpk[lo + t2];
    }
}

// ---- pass 2: per-region counting sort by src-superbucket -> pk2 + tb,
//      degrees -> dinv + z1 (half2) ----
__global__ void __launch_bounds__(1024)
buildpush(const int* __restrict__ bases1, const unsigned* __restrict__ pk1,
          const float* __restrict__ x, float* __restrict__ dinv,
          unsigned* __restrict__ z1h, unsigned* __restrict__ pk2,
          int* __restrict__ tb, int N) {
    __shared__ int deg[4096];         // 16KB: per-dst-node degree
    __shared__ int hist[16][NSB_MAX]; // 8KB: wave-replicated srcSB histogram
    __shared__ int cnt[NSB_MAX];
    __shared__ int cur[NSB_MAX];
    int reg = blockIdx.x, tid = threadIdx.x;
    int ebeg = bases1[reg], eend = bases1[reg + 1];
    int n = eend - ebeg;
    int w = tid >> 6;  // wave id 0..15
    for (int i = tid; i < 4096; i += 1024) deg[i] = 0;
    for (int i = tid; i < 16 * NSB_MAX; i += 1024) ((int*)hist)[i] = 0;
    __syncthreads();
    for (int k = tid; k < n; k += 1024) {
        unsigned p = pk1[ebeg + k];
        atomicAdd(&deg[p & 4095u], 1);
        atomicAdd(&hist[w][p >> 24], 1);
    }
    __syncthreads();
    if (tid < NSB_MAX) {
        int s = 0;
        #pragma unroll
        for (int r = 0; r < 16; ++r) s += hist[r][tid];
        cnt[tid] = s;
        cur[tid] = s;
    }
    __syncthreads();
    for (int off = 1; off < NSB_MAX; off <<= 1) {
        int a = (tid < NSB_MAX && tid >= off) ? cur[tid - off] : 0;
        __syncthreads();
        if (tid < NSB_MAX) cur[tid] += a;
        __syncthreads();
    }
    if (tid < NSB_MAX) {
        int excl = cur[tid] - cnt[tid];
        tb[reg * 129 + tid] = ebeg + excl;
        cur[tid] = excl;
    }
    if (tid == 0) tb[reg * 129 + 128] = eend;
    int node0 = reg << SBB;
    for (int t = tid; t < 4096; t += 1024) {
        int i = node0 + t;
        if (i < N) {
            float di = rsqrtf((float)deg[t] + 1.0f);
            dinv[i] = di;
            float2 xv = ((const float2*)x)[i];
            __half2 hz = __floats2half2_rn(xv.x * di, xv.y * di);
            z1h[i] = *(unsigned*)&hz;
        }
    }
    __syncthreads();
    for (int k = tid; k < n; k += 1024) {
        unsigned p = pk1[ebeg + k];
        int pos = atomicAdd(&cur[p >> 24], 1);
        pk2[ebeg + pos] = p;
    }
}

// ---------------- push kernels (LDS-staged src windows) ----------------
// block = (dstRegion, srcHalf); 64 cells of 4096 src nodes each.
// acc[4096 x F] fp32 LDS; zbuf = one staged window; next window prefetched
// into regs under current cell's LDS work.

__global__ void __launch_bounds__(1024)
push_f2(const unsigned* __restrict__ pk2, const int* __restrict__ tb,
        const unsigned* __restrict__ zt, float* __restrict__ partial, int N) {
    __shared__ float acc[8192];      // 32KB
    __shared__ unsigned zbuf[4096];  // 16KB
    int bx = blockIdx.x, tid = threadIdx.x;
    int reg = bx >> 1, h = bx & 1;
    for (int i = tid; i < 8192; i += 1024) acc[i] = 0.f;
    const int* tbr = tb + reg * 129 + h * 64;
    {
        int base = (h * 64) << SBB;
        #pragma unroll
        for (int u = 0; u < 4; ++u) {
            int idx = base + tid + u * 1024;
            zbuf[tid + u * 1024] = (idx < N) ? zt[idx] : 0u;
        }
    }
    __syncthreads();
    for (int c = 0; c < 64; ++c) {
        unsigned r[4];
        bool pf = (c + 1 < 64);
        if (pf) {
            int base = (h * 64 + c + 1) << SBB;
            #pragma unroll
            for (int u = 0; u < 4; ++u) {
                int idx = base + tid + u * 1024;
                r[u] = (idx < N) ? zt[idx] : 0u;
            }
        }
        int e0 = tbr[c], e1 = tbr[c + 1];
        for (int k = e0 + tid; k < e1; k += 1024) {
            unsigned p = __builtin_nontemporal_load(&pk2[k]);
            unsigned zr = zbuf[(p >> SBB) & 4095u];
            float2 v = __half22float2(*(__half2*)&zr);
            unsigned d = (p & 4095u) << 1;
            atomicAdd(&acc[d], v.x);
            atomicAdd(&acc[d + 1], v.y);
        }
        __syncthreads();
        if (pf) {
            #pragma unroll
            for (int u = 0; u < 4; ++u) zbuf[tid + u * 1024] = r[u];
            __syncthreads();
        }
    }
    float* pout = partial + (size_t)bx * 8192;
    for (int i = tid; i < 8192; i += 1024) pout[i] = acc[i];
}

__global__ void __launch_bounds__(1024)
push_f4(const unsigned* __restrict__ pk2, const int* __restrict__ tb,
        const unsigned long long* __restrict__ zt, float* __restrict__ partial,
        int N) {
    extern __shared__ char smem[];
    float* acc = (float*)smem;                                     // 64KB
    unsigned long long* zbuf = (unsigned long long*)(smem + 65536); // 32KB
    int bx = blockIdx.x, tid = threadIdx.x;
    int reg = bx >> 1, h = bx & 1;
    for (int i = tid; i < 16384; i += 1024) acc[i] = 0.f;
    const int* tbr = tb + reg * 129 + h * 64;
    {
        int base = (h * 64) << SBB;
        #pragma unroll
        for (int u = 0; u < 4; ++u) {
            int idx = base + tid + u * 1024;
            zbuf[tid + u * 1024] = (idx < N) ? zt[idx] : 0ull;
        }
    }
    __syncthreads();
    for (int c = 0; c < 64; ++c) {
        unsigned long long r[4];
        bool pf = (c + 1 < 64);
        if (pf) {
            int base = (h * 64 + c + 1) << SBB;
            #pragma unroll
            for (int u = 0; u < 4; ++u) {
                int idx = base + tid + u * 1024;
                r[u] = (idx < N) ? zt[idx] : 0ull;
            }
        }
        int e0 = tbr[c], e1 = tbr[c + 1];
        for (int k = e0 + tid; k < e1; k += 1024) {
            unsigned p = __builtin_nontemporal_load(&pk2[k]);
            unsigned long long zr = zbuf[(p >> SBB) & 4095u];
            unsigned lo = (unsigned)zr, hi = (unsigned)(zr >> 32);
            float2 f01 = __half22float2(*(__half2*)&lo);
            float2 f23 = __half22float2(*(__half2*)&hi);
            unsigned d = (p & 4095u) << 2;
            atomicAdd(&acc[d], f01.x);
            atomicAdd(&acc[d + 1], f01.y);
            atomicAdd(&acc[d + 2], f23.x);
            atomicAdd(&acc[d + 3], f23.y);
        }
        __syncthreads();
        if (pf) {
            #pragma unroll
            for (int u = 0; u < 4; ++u) zbuf[tid + u * 1024] = r[u];
            __syncthreads();
        }
    }
    float* pout = partial + (size_t)bx * 16384;
    for (int i = tid; i < 16384; i += 1024) pout[i] = acc[i];
}

// ---------------- finalize kernels (merge 2 partials + epilogue) ----------------

__global__ void fin1(const float* __restrict__ partial, const unsigned* __restrict__ z1h,
                     const float* __restrict__ dinv, const float* __restrict__ W1,
                     const float* __restrict__ b1, unsigned long long* __restrict__ z2h,
                     int N) {
    int i = blockIdx.x * blockDim.x + threadIdx.x;
    if (i >= N) return;
    int reg = i >> SBB, t = i & 4095;
    float a0, a1;
    {
        unsigned zr = z1h[i];
        float2 z = __half22float2(*(__half2*)&zr);
        a0 = z.x; a1 = z.y;
    }
    #pragma unroll
    for (int s = 0; s < 2; ++s) {
        size_t b = ((size_t)(reg * 2 + s) * 4096 + t) * 2;
        a0 += partial[b];
        a1 += partial[b + 1];
    }
    float di = dinv[i];
    float g0 = di * a0, g1 = di * a1;
    float o0 = di * tanhf(fmaf(g0, W1[0], fmaf(g1, W1[4], b1[0])));
    float o1 = di * tanhf(fmaf(g0, W1[1], fmaf(g1, W1[5], b1[1])));
    float o2 = di * tanhf(fmaf(g0, W1[2], fmaf(g1, W1[6], b1[2])));
    float o3 = di * tanhf(fmaf(g0, W1[3], fmaf(g1, W1[7], b1[3])));
    __half2 ha = __floats2half2_rn(o0, o1);
    __half2 hb = __floats2half2_rn(o2, o3);
    unsigned long long pk = (unsigned long long)(*(unsigned*)&ha) |
                            ((unsigned long long)(*(unsigned*)&hb) << 32);
    z2h[i] = pk;
}

__global__ void fin2(const float* __restrict__ partial,
                     const unsigned long long* __restrict__ z2h,
                     const float* __restrict__ dinv, const float* __restrict__ W2,
                     const float* __restrict__ b2, const float* __restrict__ W3,
                     unsigned* __restrict__ z3h, int N) {
    int i = blockIdx.x * blockDim.x + threadIdx.x;
    if (i >= N) return;
    int reg = i >> SBB, t = i & 4095;
    float a0, a1, a2, a3;
    {
        unsigned long long zr = z2h[i];
        unsigned lo = (unsigned)zr, hi = (unsigned)(zr >> 32);
        float2 f01 = __half22float2(*(__half2*)&lo);
        float2 f23 = __half22float2(*(__half2*)&hi);
        a0 = f01.x; a1 = f01.y; a2 = f23.x; a3 = f23.y;
    }
    #pragma unroll
    for (int s = 0; s < 2; ++s) {
        size_t b = ((size_t)(reg * 2 + s) * 4096 + t) * 4;
        a0 += partial[b];
        a1 += partial[b + 1];
        a2 += partial[b + 2];
        a3 += partial[b + 3];
    }
    float di = dinv[i];
    float g0 = di * a0, g1 = di * a1, g2 = di * a2, g3 = di * a3;
    float h[4];
    #pragma unroll
    for (int c = 0; c < 4; ++c)
        h[c] = tanhf(b2[c] + g0 * W2[c] + g1 * W2[4 + c] + g2 * W2[8 + c] + g3 * W2[12 + c]);
    float v0 = h[0] * W3[0] + h[1] * W3[2] + h[2] * W3[4] + h[3] * W3[6];
    float v1 = h[0] * W3[1] + h[1] * W3[3] + h[2] * W3[5] + h[3] * W3[7];
    __half2 hz = __floats2half2_rn(v0 * di, v1 * di);
    z3h[i] = *(unsigned*)&hz;
}

__global__ void fin3(const float* __restrict__ partial, const unsigned* __restrict__ z3h,
                     const float* __restrict__ dinv, const float* __restrict__ b3,
                     float* __restrict__ out, int N) {
    int i = blockIdx.x * blockDim.x + threadIdx.x;
    if (i >= N) return;
    int reg = i >> SBB, t = i & 4095;
    float a0, a1;
    {
        unsigned zr = z3h[i];
        float2 z = __half22float2(*(__half2*)&zr);
        a0 = z.x; a1 = z.y;
    }
    #pragma unroll
    for (int s = 0; s < 2; ++s) {
        size_t b = ((size_t)(reg * 2 + s) * 4096 + t) * 2;
        a0 += partial[b];
        a1 += partial[b + 1];
    }
    float di = dinv[i];
    ((float2*)out)[i] = make_float2(fmaf(di, a0, b3[0]), fmaf(di, a1, b3[1]));
}

extern "C" void kernel_launch(void* const* d_in, const int* in_sizes, int n_in,
                              void* d_out, int out_size, void* d_ws, size_t ws_size,
                              hipStream_t stream) {
    const float* x  = (const float*)d_in[0];
    const int*   ei = (const int*)d_in[1];
    const float* W1 = (const float*)d_in[2];
    const float* b1 = (const float*)d_in[3];
    const float* W2 = (const float*)d_in[4];
    const float* b2 = (const float*)d_in[5];
    const float* W3 = (const float*)d_in[6];
    const float* b3 = (const float*)d_in[7];
    float* out = (float*)d_out;

    const int N = in_sizes[0] / 2;
    const int E = in_sizes[1] / 2;
    const int* src = ei;
    const int* dst = ei + E;

    const int SB  = (N + (1 << SBB) - 1) >> SBB;     // 123 superbuckets
    const int ntB = (E + T_TILE - 1) / T_TILE;       // 977 tiles of 16K edges
    const int mlen = SB * ntB;                       // ~120K
    const int NB = (mlen + 1023) / 1024;             // ~118

    // allow 96KB dynamic LDS for push_f4 (gfx950: 160KB/workgroup)
    static bool attr_done = false;
    if (!attr_done) {
        hipFuncSetAttribute((const void*)push_f4,
                            hipFuncAttributeMaxDynamicSharedMemorySize, 98304);
        attr_done = true;
    }

    // ws layout (256B-aligned)
    auto align = [](size_t o) { return (o + 255) & ~(size_t)255; };
    char* wbase = (char*)d_ws;
    size_t off = 0;
    float*    dinv   = (float*)(wbase + off);    off = align(off + (size_t)N * 4);
    unsigned* z1h    = (unsigned*)(wbase + off); off = align(off + (size_t)N * 4);
    unsigned long long* z2h = (unsigned long long*)(wbase + off);
    off = align(off + (size_t)N * 8);
    unsigned* z3h    = (unsigned*)(wbase + off); off = align(off + (size_t)N * 4);
    int*      tb     = (int*)(wbase + off);      off = align(off + (size_t)SB * 129 * 4);
    int*      bsum   = (int*)(wbase + off);      off = align(off + (size_t)1024 * 4);
    int*      bases1 = (int*)(wbase + off);      off = align(off + (size_t)(SB + 1) * 4);
    int*      cnt1   = (int*)(wbase + off);      off = align(off + (size_t)mlen * 4);
    unsigned* pk1    = (unsigned*)(wbase + off); off = align(off + (size_t)E * 4);
    unsigned* pk2    = (unsigned*)(wbase + off); off = align(off + (size_t)E * 4);
    // partial[2 halves][4096 nodes][<=4 feats] fp32 per region = 16.1MB max;
    // aliases pk1 (dead after buildpush).
    float* partial = (float*)pk1;

    const int NBLK = SB * 2;  // 246 push blocks

    dim3 gN((N + TPB - 1) / TPB);
    count1<<<dim3(ntB), dim3(512), 0, stream>>>(dst, cnt1, ntB, E, SB);
    scan_k1<<<dim3(NB), dim3(TPB), 0, stream>>>(cnt1, bsum, mlen);
    scan_k2<<<dim3(1), dim3(1024), 0, stream>>>(bsum, NB);
    scan_k3<<<dim3(NB), dim3(TPB), 0, stream>>>(cnt1, bsum, mlen);
    bases_fix<<<dim3(1), dim3(256), 0, stream>>>(cnt1, ntB, SB, bases1, E);
    scatter1<<<dim3(ntB), dim3(512), 0, stream>>>(dst, src, cnt1, pk1, ntB, E, SB);
    buildpush<<<dim3(SB), dim3(1024), 0, stream>>>(bases1, pk1, x, dinv, z1h, pk2, tb, N);

    push_f2<<<dim3(NBLK), dim3(1024), 0, stream>>>(pk2, tb, z1h, partial, N);
    fin1<<<gN, dim3(TPB), 0, stream>>>(partial, z1h, dinv, W1, b1, z2h, N);
    push_f4<<<dim3(NBLK), dim3(1024), 98304, stream>>>(pk2, tb, z2h, partial, N);
    fin2<<<gN, dim3(TPB), 0, stream>>>(partial, z2h, dinv, W2, b2, W3, z3h, N);
    push_f2<<<dim3(NBLK), dim3(1024), 0, stream>>>(pk2, tb, z3h, partial, N);
    fin3<<<gN, dim3(TPB), 0, stream>>>(partial, z3h, dinv, b3, out, N);
}

// Round 8
// 715.414 us; speedup vs baseline: 1.8872x; 1.8872x over previous
//
#include <hip/hip_runtime.h>
#include <hip/hip_fp16.h>

// GCN 3-layer, pull-mode layers (R16-proven) + lean build (R21).
// R19/R20 push-mode abandoned per falsifier (LDS-staged push 3x worse than
// pull: barrier-serialized cells + LDS-atomic RMW, 360-423us/layer).
// Layers sit at the per-XCD L2 random-request wall (~8.1us per M gathers;
// R17 residency + R18 L1-bypass both null) -> R21 attacks build instead:
// - count1 + 3 scan kernels REPLACED by atomic reservation: each fine bucket
//   (1024 nodes, dst>>10, 489 buckets) owns a fixed CAP_F=34048 (+7 sigma)
//   region of pk1; scatter1 LDS-aggregates per-tile histograms and reserves
//   chunks with one global atomicAdd per bucket. bases_fix scans the 489
//   final counts (1 block) -> compact csr bases.
// - scatter1 sorts DIRECTLY into fine buckets (was superbuckets of 4096):
//   buildfine now reads only its own ~33K edges x2 (131MB total vs R16's
//   516MB 4x-over-read) and drops all fine-id filtering machinery.
// R13: z2 4xfp16 (8B/node). R14: z1/z3 half2 (4B/node). R16: in-LDS
// counting-sort scatter (coalesced flush).
// Math per layer (input u): z = u*dinv; s_i = sum_{e:dst=i} z[src_e];
//   out_i = (dinv_i*(s_i + z_i)) @ W + b   (self-loop folds into s+z).
// pk1 = (dst&1023) | (src<<10)  (29 bits, N < 2^19).

#define TPB 256
#define T_TILE 16384
#define FBB 10           // fine bucket = 1024 nodes
#define FB_MAX 512
#define CAP_F 34048      // per-bucket pk1 capacity: mean 32.7K, +7 sigma
#define EB_CAP 34048

// ---- init: bucket reservation cursors ----
__global__ void initcur(int* __restrict__ cur, int FB) {
    int t = threadIdx.x;
    if (t < FB) cur[t] = t * CAP_F;
}

// ---- pass 1: in-LDS counting-sort scatter into fine buckets ----
__global__ void __launch_bounds__(512)
scatter1(const int* __restrict__ dst, const int* __restrict__ src,
         int* __restrict__ cur, unsigned* __restrict__ pk1, int E, int FB) {
    __shared__ unsigned lpk[T_TILE];   // 64KB staged packed values
    __shared__ int lhist[FB_MAX];
    __shared__ int lexcl[FB_MAX];
    __shared__ int lcur[FB_MAX];
    __shared__ int lbase[FB_MAX];
    int blk = blockIdx.x, tid = threadIdx.x;
    lhist[tid] = 0;
    __syncthreads();
    int base = blk * T_TILE;
    // pass A: tile histogram over fine buckets (dst slice L2-hot for pass B)
    #pragma unroll 8
    for (int it = 0; it < T_TILE / 512; ++it) {
        int e = base + it * 512 + tid;
        if (e < E) atomicAdd(&lhist[((unsigned)dst[e]) >> FBB], 1);
    }
    __syncthreads();
    // exclusive scan over 512 bucket counts (FB=489 used)
    int hv = lhist[tid];
    lexcl[tid] = hv;
    __syncthreads();
    for (int off = 1; off < FB_MAX; off <<= 1) {
        int a = (tid >= off) ? lexcl[tid - off] : 0;
        __syncthreads();
        lexcl[tid] += a;
        __syncthreads();
    }
    lexcl[tid] -= hv;
    lcur[tid] = lexcl[tid];
    // reserve global chunk per bucket (one atomic per non-empty bucket)
    if (tid < FB && hv > 0) lbase[tid] = atomicAdd(&cur[tid], hv);
    __syncthreads();
    // pass B: place packed values into LDS at sorted positions
    #pragma unroll 8
    for (int it = 0; it < T_TILE / 512; ++it) {
        int e = base + it * 512 + tid;
        if (e < E) {
            unsigned d = (unsigned)dst[e];
            unsigned s = (unsigned)src[e];
            int pos = atomicAdd(&lcur[d >> FBB], 1);
            lpk[pos] = (d & 1023u) | (s << FBB);
        }
    }
    __syncthreads();
    // flush: wave-parallel per-bucket contiguous copy (coalesced-ish, ~33/bucket)
    int w = tid >> 6, lane = tid & 63;
    for (int fb = w; fb < FB; fb += 8) {
        int cntb = lhist[fb];
        if (cntb == 0) continue;
        int lo = lexcl[fb], gb = lbase[fb];
        for (int t2 = lane; t2 < cntb; t2 += 64)
            pk1[gb + t2] = lpk[lo + t2];
    }
}

// ---- compact csr bases from final cursors (single block) ----
__global__ void bases_fix(const int* __restrict__ cur, int* __restrict__ csrbase,
                          int* __restrict__ rowptr, int FB, int N, int E) {
    __shared__ int lds[FB_MAX];
    int t = threadIdx.x;
    int c = (t < FB) ? (cur[t] - t * CAP_F) : 0;
    lds[t] = c;
    __syncthreads();
    for (int off = 1; off < FB_MAX; off <<= 1) {
        int a = (t >= off) ? lds[t - off] : 0;
        __syncthreads();
        lds[t] += a;
        __syncthreads();
    }
    if (t < FB) csrbase[t] = lds[t] - c;  // exclusive
    if (t == 0) { csrbase[FB] = E; rowptr[N] = E; }
}

// ---- pass 2: per-fine-bucket node sort -> csr + rowptr + dinv + z1 ----
__global__ void __launch_bounds__(1024)
buildfine(const unsigned* __restrict__ pk1, const int* __restrict__ csrbase,
          const float* __restrict__ x, int* __restrict__ rowptr,
          float* __restrict__ dinv, unsigned* __restrict__ z1h,
          unsigned* __restrict__ csr, int N) {
    __shared__ int cnt[1024];
    __shared__ int tmp[1024];
    __shared__ int cur[1024];
    __shared__ unsigned eb[EB_CAP];
    int fb = blockIdx.x, tid = threadIdx.x;
    int cb = csrbase[fb];
    int n = csrbase[fb + 1] - cb;
    size_t pbase = (size_t)fb * CAP_F;
    cnt[tid] = 0;
    __syncthreads();
    // pass A: per-node degree
    int k0 = 0;
    for (; k0 + 8192 <= n; k0 += 8192) {
        unsigned p[8];
        #pragma unroll
        for (int u = 0; u < 8; ++u) p[u] = pk1[pbase + k0 + tid + u * 1024];
        #pragma unroll
        for (int u = 0; u < 8; ++u) atomicAdd(&cnt[p[u] & 1023u], 1);
    }
    for (int k = k0 + tid; k < n; k += 1024)
        atomicAdd(&cnt[pk1[pbase + k] & 1023u], 1);
    __syncthreads();
    // scan 1024 node counts
    int c = cnt[tid];
    tmp[tid] = c;
    __syncthreads();
    for (int o = 1; o < 1024; o <<= 1) {
        int a = (tid >= o) ? tmp[tid - o] : 0;
        __syncthreads();
        tmp[tid] += a;
        __syncthreads();
    }
    int excl = tmp[tid] - c;
    int i = (fb << FBB) + tid;
    if (i < N) {
        rowptr[i] = cb + excl;
        float di = rsqrtf((float)c + 1.0f);
        dinv[i] = di;
        float2 xv = ((const float2*)x)[i];
        __half2 hz = __floats2half2_rn(xv.x * di, xv.y * di);
        z1h[i] = *(unsigned*)&hz;
    }
    cur[tid] = excl;
    __syncthreads();
    // pass B: place srcs sorted by node
    if (n <= EB_CAP) {
        k0 = 0;
        for (; k0 + 8192 <= n; k0 += 8192) {
            unsigned p[8];
            #pragma unroll
            for (int u = 0; u < 8; ++u) p[u] = pk1[pbase + k0 + tid + u * 1024];
            #pragma unroll
            for (int u = 0; u < 8; ++u) {
                int pos = atomicAdd(&cur[p[u] & 1023u], 1);
                eb[pos] = p[u] >> FBB;
            }
        }
        for (int k = k0 + tid; k < n; k += 1024) {
            unsigned p = pk1[pbase + k];
            int pos = atomicAdd(&cur[p & 1023u], 1);
            eb[pos] = p >> FBB;
        }
        __syncthreads();
        for (int k = tid; k < n; k += 1024) csr[cb + k] = eb[k];
    } else {
        for (int k = tid; k < n; k += 1024) {
            unsigned p = pk1[pbase + k];
            int pos = atomicAdd(&cur[p & 1023u], 1);
            csr[cb + pos] = p >> FBB;
        }
    }
}

// ---------------- GCN layers (R16-proven pull mode) ----------------

__global__ void gcn1(const int* __restrict__ rowptr, const unsigned* __restrict__ csr,
                     const unsigned* __restrict__ z1h, const float* __restrict__ W1,
                     const float* __restrict__ b1, const float* __restrict__ dinv,
                     uint2* __restrict__ z2h, int N) {
    int i = blockIdx.x * blockDim.x + threadIdx.x;
    if (i >= N) return;
    int r0 = rowptr[i], r1 = rowptr[i + 1];
    float a0, a1;
    {
        unsigned zr = z1h[i];
        float2 zi = __half22float2(*(__half2*)&zr);
        a0 = zi.x; a1 = zi.y;
    }
    int k = r0;
    for (; k + 16 <= r1; k += 16) {
        unsigned j[16];
        #pragma unroll
        for (int u = 0; u < 16; ++u) j[u] = __builtin_nontemporal_load(&csr[k + u]);
        unsigned raw[16];
        #pragma unroll
        for (int u = 0; u < 16; ++u) raw[u] = z1h[j[u]];
        #pragma unroll
        for (int u = 0; u < 16; ++u) {
            float2 v = __half22float2(*(__half2*)&raw[u]);
            a0 += v.x; a1 += v.y;
        }
    }
    for (; k < r1; ++k) {
        unsigned zr = z1h[csr[k]];
        float2 zv = __half22float2(*(__half2*)&zr);
        a0 += zv.x; a1 += zv.y;
    }
    float di = dinv[i];
    float g0 = di * a0, g1 = di * a1;
    float o0 = di * tanhf(fmaf(g0, W1[0], fmaf(g1, W1[4], b1[0])));
    float o1 = di * tanhf(fmaf(g0, W1[1], fmaf(g1, W1[5], b1[1])));
    float o2 = di * tanhf(fmaf(g0, W1[2], fmaf(g1, W1[6], b1[2])));
    float o3 = di * tanhf(fmaf(g0, W1[3], fmaf(g1, W1[7], b1[3])));
    __half2 ha = __floats2half2_rn(o0, o1);
    __half2 hb = __floats2half2_rn(o2, o3);
    uint2 packed;
    packed.x = *(unsigned*)&ha;
    packed.y = *(unsigned*)&hb;
    z2h[i] = packed;
}

__global__ void gcn2(const int* __restrict__ rowptr, const unsigned* __restrict__ csr,
                     const uint2* __restrict__ z2h, const float* __restrict__ W2,
                     const float* __restrict__ b2, const float* __restrict__ W3,
                     const float* __restrict__ dinv, unsigned* __restrict__ z3h, int N) {
    int i = blockIdx.x * blockDim.x + threadIdx.x;
    if (i >= N) return;
    int r0 = rowptr[i], r1 = rowptr[i + 1];
    float a0, a1, a2, a3;
    {
        uint2 raw = z2h[i];
        float2 f01 = __half22float2(*(__half2*)&raw.x);
        float2 f23 = __half22float2(*(__half2*)&raw.y);
        a0 = f01.x; a1 = f01.y; a2 = f23.x; a3 = f23.y;
    }
    int k = r0;
    for (; k + 8 <= r1; k += 8) {
        unsigned j[8];
        #pragma unroll
        for (int u = 0; u < 8; ++u) j[u] = __builtin_nontemporal_load(&csr[k + u]);
        uint2 raw[8];
        #pragma unroll
        for (int u = 0; u < 8; ++u) raw[u] = z2h[j[u]];
        #pragma unroll
        for (int u = 0; u < 8; ++u) {
            float2 f01 = __half22float2(*(__half2*)&raw[u].x);
            float2 f23 = __half22float2(*(__half2*)&raw[u].y);
            a0 += f01.x; a1 += f01.y; a2 += f23.x; a3 += f23.y;
        }
    }
    for (; k < r1; ++k) {
        uint2 raw = z2h[csr[k]];
        float2 f01 = __half22float2(*(__half2*)&raw.x);
        float2 f23 = __half22float2(*(__half2*)&raw.y);
        a0 += f01.x; a1 += f01.y; a2 += f23.x; a3 += f23.y;
    }
    float di = dinv[i];
    float g0 = di * a0, g1 = di * a1, g2 = di * a2, g3 = di * a3;
    float h[4];
    #pragma unroll
    for (int c = 0; c < 4; ++c)
        h[c] = tanhf(b2[c] + g0 * W2[c] + g1 * W2[4 + c] + g2 * W2[8 + c] + g3 * W2[12 + c]);
    float v0 = h[0] * W3[0] + h[1] * W3[2] + h[2] * W3[4] + h[3] * W3[6];
    float v1 = h[0] * W3[1] + h[1] * W3[3] + h[2] * W3[5] + h[3] * W3[7];
    __half2 hz = __floats2half2_rn(v0 * di, v1 * di);
    z3h[i] = *(unsigned*)&hz;
}

__global__ void gcn3(const int* __restrict__ rowptr, const unsigned* __restrict__ csr,
                     const unsigned* __restrict__ z3h, const float* __restrict__ b3,
                     const float* __restrict__ dinv, float* __restrict__ out, int N) {
    int i = blockIdx.x * blockDim.x + threadIdx.x;
    if (i >= N) return;
    int r0 = rowptr[i], r1 = rowptr[i + 1];
    float a0, a1;
    {
        unsigned zr = z3h[i];
        float2 zi = __half22float2(*(__half2*)&zr);
        a0 = zi.x; a1 = zi.y;
    }
    int k = r0;
    for (; k + 16 <= r1; k += 16) {
        unsigned j[16];
        #pragma unroll
        for (int u = 0; u < 16; ++u) j[u] = __builtin_nontemporal_load(&csr[k + u]);
        unsigned raw[16];
        #pragma unroll
        for (int u = 0; u < 16; ++u) raw[u] = z3h[j[u]];
        #pragma unroll
        for (int u = 0; u < 16; ++u) {
            float2 v = __half22float2(*(__half2*)&raw[u]);
            a0 += v.x; a1 += v.y;
        }
    }
    for (; k < r1; ++k) {
        unsigned zr = z3h[csr[k]];
        float2 zv = __half22float2(*(__half2*)&zr);
        a0 += zv.x; a1 += zv.y;
    }
    float di = dinv[i];
    ((float2*)out)[i] = make_float2(fmaf(di, a0, b3[0]), fmaf(di, a1, b3[1]));
}

extern "C" void kernel_launch(void* const* d_in, const int* in_sizes, int n_in,
                              void* d_out, int out_size, void* d_ws, size_t ws_size,
                              hipStream_t stream) {
    const float* x  = (const float*)d_in[0];
    const int*   ei = (const int*)d_in[1];
    const float* W1 = (const float*)d_in[2];
    const float* b1 = (const float*)d_in[3];
    const float* W2 = (const float*)d_in[4];
    const float* b2 = (const float*)d_in[5];
    const float* W3 = (const float*)d_in[6];
    const float* b3 = (const float*)d_in[7];
    float* out = (float*)d_out;

    const int N = in_sizes[0] / 2;
    const int E = in_sizes[1] / 2;
    const int* src = ei;
    const int* dst = ei + E;

    const int FB  = (N + (1 << FBB) - 1) >> FBB;     // 489 fine buckets
    const int ntB = (E + T_TILE - 1) / T_TILE;       // 977 tiles of 16K edges

    // ws layout (256B-aligned)
    auto align = [](size_t o) { return (o + 255) & ~(size_t)255; };
    char* wbase = (char*)d_ws;
    size_t off = 0;
    float*    dinv    = (float*)(wbase + off);    off = align(off + (size_t)N * 4);
    unsigned* z1h     = (unsigned*)(wbase + off); off = align(off + (size_t)N * 4);
    uint2*    z2h     = (uint2*)(wbase + off);    off = align(off + (size_t)N * 8);
    unsigned* z3h     = (unsigned*)(wbase + off); off = align(off + (size_t)N * 4);
    int*      rowptr  = (int*)(wbase + off);      off = align(off + (size_t)(N + 1) * 4);
    int*      cur     = (int*)(wbase + off);      off = align(off + (size_t)FB_MAX * 4);
    int*      csrbase = (int*)(wbase + off);      off = align(off + (size_t)(FB_MAX + 1) * 4);
    unsigned* pk1     = (unsigned*)(wbase + off); off = align(off + (size_t)FB * CAP_F * 4);
    unsigned* csr     = (unsigned*)(wbase + off); off = align(off + (size_t)E * 4);

    dim3 gN((N + TPB - 1) / TPB);
    initcur<<<dim3(1), dim3(512), 0, stream>>>(cur, FB);
    scatter1<<<dim3(ntB), dim3(512), 0, stream>>>(dst, src, cur, pk1, E, FB);
    bases_fix<<<dim3(1), dim3(512), 0, stream>>>(cur, csrbase, rowptr, FB, N, E);
    buildfine<<<dim3(FB), dim3(1024), 0, stream>>>(pk1, csrbase, x, rowptr, dinv,
                                                   z1h, csr, N);
    gcn1<<<gN, dim3(TPB), 0, stream>>>(rowptr, csr, z1h, W1, b1, dinv, z2h, N);
    gcn2<<<gN, dim3(TPB), 0, stream>>>(rowptr, csr, z2h, W2, b2, W3, dinv, z3h, N);
    gcn3<<<gN, dim3(TPB), 0, stream>>>(rowptr, csr, z3h, b3, dinv, out, N);
}